// Round 14
// baseline (255.008 us; speedup 1.0000x reference)
//
#include <hip/hip_runtime.h>
#include <hip/hip_bf16.h>

#define N_NODES 1048576
#define H 128
#define B_SESS 4096
#define TILE 64
#define TPB 4          // tiles per block (block covers 256 nodes)

typedef __attribute__((ext_vector_type(8))) short bf16x8;
typedef __attribute__((ext_vector_type(4))) short bf16x4;
typedef __attribute__((ext_vector_type(4))) float f32x4;

__device__ inline short bc(float f) {
  return (short)__builtin_bit_cast(unsigned short, __float2bfloat16(f));
}

// ---------------------------------------------------------------- kernel 1
// fused prep: last-index scan + s_g zero + W2 f32->bf16 (linear)
__global__ void k_prep(const int* __restrict__ batch, int* __restrict__ last_idx,
                       const float* __restrict__ W2, unsigned short* __restrict__ W2b,
                       float* __restrict__ s_g) {
  int i = blockIdx.x * 256 + threadIdx.x;
  if (i < N_NODES) {
    if (i == N_NODES - 1 || batch[i] != batch[i + 1]) last_idx[batch[i]] = i;
  }
  if (i < B_SESS * H) s_g[i] = 0.f;
  if (i < 4096) {
    float4 v = *reinterpret_cast<const float4*>(W2 + (size_t)i * 4);
    bf16x4 o;
    o[0] = bc(v.x); o[1] = bc(v.y); o[2] = bc(v.z); o[3] = bc(v.w);
    *reinterpret_cast<bf16x4*>(W2b + (size_t)i * 4) = o;
  }
}

// ---------------------------------------------------------------- kernel 2
// A_pre[b,h] = v_n[b] . W1[h,:] + b1[h] + b2[h]
__global__ void k_apre(const float* __restrict__ x, const int* __restrict__ last_idx,
                       const float* __restrict__ W1, const float* __restrict__ b1,
                       const float* __restrict__ b2, float* __restrict__ A_pre) {
  __shared__ float Wl[128][132];
  __shared__ float vn[8][128];
  int t = threadIdx.x;
  for (int i = 0; i < 16; ++i) {
    int e = (t + i * 256) * 4;
    int r = e >> 7, c = e & 127;
    float4 v = *reinterpret_cast<const float4*>(W1 + e);
    Wl[r][c] = v.x; Wl[r][c + 1] = v.y; Wl[r][c + 2] = v.z; Wl[r][c + 3] = v.w;
  }
  int b0 = blockIdx.x * 8;
  for (int i = t; i < 8 * 128; i += 256) {
    int s = i >> 7, c = i & 127;
    vn[s][c] = x[(size_t)last_idx[b0 + s] * H + c];
  }
  __syncthreads();
  int h = t & 127, si = t >> 7;
  float bias = b1[h] + b2[h];
  for (int s = si; s < 8; s += 2) {
    float acc = bias;
    #pragma unroll
    for (int k = 0; k < 128; k += 4) {
      float4 w = *reinterpret_cast<const float4*>(&Wl[h][k]);
      acc += vn[s][k] * w.x + vn[s][k + 1] * w.y + vn[s][k + 2] * w.z + vn[s][k + 3] * w.w;
    }
    A_pre[(size_t)(b0 + s) * H + h] = acc;
  }
}

// ---------------------------------------------------------------- kernel 3
// R6 skeleton + cross-tile af prefetch: 4 tiles/block, W2 in LDS once (async),
// af(t+1) issued into registers before tile t's MFMA -> HBM stays busy during
// compute.  Double-buffered per-tile metadata (bsegs/apre_s/alph) in LDS.
__global__ __launch_bounds__(256, 4)
void k_main(const float* __restrict__ x, const int* __restrict__ batch,
            const unsigned short* __restrict__ W2b, const float* __restrict__ Wq,
            const float* __restrict__ bq, const float* __restrict__ A_pre,
            float* __restrict__ s_g) {
  __shared__ unsigned short Wl[128 * 128];   // bf16 W2, linear (32 KB)
  __shared__ float apre2[2][4][128];         // staged A_pre rows (fast path)
  __shared__ float alph2[2][TILE];
  __shared__ int bseg2[2][TILE + 1];
  __shared__ float wqs[128];
  int t = threadIdx.x;
  int w = t >> 6, lane = t & 63, r = lane & 15, ks = lane >> 4;
  int base0 = blockIdx.x * (TILE * TPB);

  // ---- W2 -> LDS once, async (no VGPR round-trip)
  #pragma unroll
  for (int i = 0; i < 8; ++i) {
    int seg = w * 8 + i;                     // 32 x 1KB chunks
    __builtin_amdgcn_global_load_lds(
        reinterpret_cast<const unsigned int*>(
            reinterpret_cast<const char*>(W2b) + seg * 1024 + lane * 16),
        reinterpret_cast<unsigned int*>(
            reinterpret_cast<char*>(&Wl[0]) + seg * 1024),
        16, 0, 0);
  }
  if (t < 128) wqs[t] = Wq[t];
  float bqv = bq[0];

  // ---- prologue: issue af(0), stage meta(0) into parity 0
  float4 af[8];
  {
    const float* xrow = x + (size_t)(base0 + w * 16 + r) * H;
    #pragma unroll
    for (int k = 0; k < 4; ++k) {
      af[2 * k]     = *reinterpret_cast<const float4*>(xrow + k * 32 + ks * 8);
      af[2 * k + 1] = *reinterpret_cast<const float4*>(xrow + k * 32 + ks * 8 + 4);
    }
    if (t <= TILE) {
      int idx = base0 + t;
      bseg2[0][t] = (idx < N_NODES) ? batch[idx] : -1;
    }
    int s0 = batch[base0], s1 = batch[base0 + TILE - 1];
    int cnt = s1 - s0 + 1;
    if (cnt <= 4) {
      const float4* src = reinterpret_cast<const float4*>(A_pre + ((size_t)s0 << 7));
      float4* dst = reinterpret_cast<float4*>(&apre2[0][0][0]);
      for (int i = t; i < cnt * 32; i += 256) dst[i] = src[i];
    }
  }
  __syncthreads();                           // Wl + meta(0) ready

  // ---- tile loop
  for (int tt = 0; tt < TPB; ++tt) {
    int par = tt & 1;
    int node0 = base0 + tt * TILE;

    // convert current af -> bf16 (drains af's vmcnt)
    bf16x8 afr[4];
    #pragma unroll
    for (int kg = 0; kg < 4; ++kg) {
      const float* afp = reinterpret_cast<const float*>(af);
      bf16x8 v;
      #pragma unroll
      for (int c = 0; c < 8; ++c) v[c] = bc(afp[kg * 8 + c]);
      afr[kg] = v;
    }

    // ---- issue af(t+1) NOW: in flight across MFMA+alpha+phase2
    if (tt + 1 < TPB) {
      const float* xrow = x + (size_t)(node0 + TILE + w * 16 + r) * H;
      #pragma unroll
      for (int k = 0; k < 4; ++k) {
        af[2 * k]     = *reinterpret_cast<const float4*>(xrow + k * 32 + ks * 8);
        af[2 * k + 1] = *reinterpret_cast<const float4*>(xrow + k * 32 + ks * 8 + 4);
      }
      // stage meta(t+1) into the other parity
      if (t <= TILE) {
        int idx = node0 + TILE + t;
        bseg2[par ^ 1][t] = (idx < N_NODES) ? batch[idx] : -1;
      }
      int s0 = batch[node0 + TILE], s1 = batch[node0 + TILE + TILE - 1];
      int cnt = s1 - s0 + 1;
      if (cnt <= 4) {
        const float4* src = reinterpret_cast<const float4*>(A_pre + ((size_t)s0 << 7));
        float4* dst = reinterpret_cast<float4*>(&apre2[par ^ 1][0][0]);
        for (int i = t; i < cnt * 32; i += 256) dst[i] = src[i];
      }
    }

    // ---- MFMA: z partials (C layout: row = ks*4+j, col = nt*16+r)
    f32x4 acc[8];
    #pragma unroll
    for (int nt = 0; nt < 8; ++nt) acc[nt] = (f32x4){0.f, 0.f, 0.f, 0.f};
    #pragma unroll
    for (int kg = 0; kg < 4; ++kg) {
      #pragma unroll
      for (int nt = 0; nt < 8; ++nt) {
        bf16x8 b = *reinterpret_cast<const bf16x8*>(
            &Wl[(nt * 16 + r) * 128 + kg * 32 + ks * 8]);
        acc[nt] = __builtin_amdgcn_mfma_f32_16x16x32_bf16(afr[kg], b, acc[nt], 0, 0, 0);
      }
    }

    // ---- alpha: sigmoid + Wq-dot + 16-lane reduce
    int smin = bseg2[par][0];
    bool fast = (bseg2[par][TILE - 1] - smin) <= 3;
    float pa[4];
#define DO_ALPHA(GET) do {                                                   \
    _Pragma("unroll")                                                        \
    for (int j = 0; j < 4; ++j) {                                            \
      int row = bseg2[par][w * 16 + ks * 4 + j];                             \
      float s = 0.f;                                                         \
      _Pragma("unroll")                                                      \
      for (int nt = 0; nt < 8; ++nt) {                                       \
        int col = nt * 16 + r;                                               \
        float z = acc[nt][j] + (GET);                                        \
        float g = 1.0f / (1.0f + __expf(-z));                                \
        s += g * wqs[col];                                                   \
      }                                                                      \
      s += __shfl_xor(s, 1); s += __shfl_xor(s, 2);                          \
      s += __shfl_xor(s, 4); s += __shfl_xor(s, 8);                          \
      pa[j] = s + bqv;                                                       \
    } } while (0)
    if (fast) DO_ALPHA(apre2[par][row - smin][col]);
    else      DO_ALPHA(A_pre[(size_t)row * H + col]);
#undef DO_ALPHA
    if (r == 0) {
      #pragma unroll
      for (int j = 0; j < 4; ++j) alph2[par][w * 16 + ks * 4 + j] = pa[j];
    }
    __syncthreads();                         // alph(t) + meta(t+1) ready

    // ---- phase 2: s_g[b,h] += alpha_i * x[i,h]  (x from L1/L2, chunked)
    {
      int h = t & 127, grp = t >> 7;         // 2 groups x 32 nodes
      int base = grp * 32;
      const float* xp = x + (size_t)(node0 + base) * H + h;
      float accum = 0.f;
      #pragma unroll
      for (int c = 0; c < 2; ++c) {
        float xvv[16];
        #pragma unroll
        for (int n = 0; n < 16; ++n) xvv[n] = xp[(size_t)(c * 16 + n) * H];
        #pragma unroll
        for (int n = 0; n < 16; ++n) {
          int ln = base + c * 16 + n;
          accum += alph2[par][ln] * xvv[n];
          if (bseg2[par][ln] != bseg2[par][ln + 1]) {
            atomicAdd(&s_g[((size_t)bseg2[par][ln] << 7) + h], accum);
            accum = 0.f;
          }
        }
      }
      if (accum != 0.f)
        atomicAdd(&s_g[((size_t)bseg2[par][base + 31] << 7) + h], accum);
    }
    __syncthreads();                         // phase2 done before meta(par) reuse
  }
}

// ---------------------------------------------------------------- kernel 4
// s_h[b,h] = b3[h] + concat(v_n[b], s_g[b]) . W3[h,:]
__global__ void k_final(const float* __restrict__ x, const int* __restrict__ last_idx,
                        const float* __restrict__ s_g, const float* __restrict__ W3,
                        const float* __restrict__ b3, float* __restrict__ out) {
  __shared__ float Wl[128][132];
  __shared__ float vin[8][256];
  int t = threadIdx.x;
  int b0 = blockIdx.x * 8;
  for (int i = t; i < 8 * 256; i += 256) {
    int s = i >> 8, c = i & 255;
    float v;
    if (c < 128) v = x[(size_t)last_idx[b0 + s] * H + c];
    else         v = s_g[(size_t)(b0 + s) * H + (c - 128)];
    vin[s][c] = v;
  }
  int h = t & 127, si = t >> 7;
  float res[4];
  for (int half = 0; half < 2; ++half) {
    __syncthreads();
    for (int i = 0; i < 16; ++i) {
      int e = (t + i * 256) * 4;
      int r = e >> 7, c = e & 127;
      float4 v = *reinterpret_cast<const float4*>(W3 + (size_t)r * 256 + half * 128 + c);
      Wl[r][c] = v.x; Wl[r][c + 1] = v.y; Wl[r][c + 2] = v.z; Wl[r][c + 3] = v.w;
    }
    __syncthreads();
    #pragma unroll
    for (int sI = 0; sI < 4; ++sI) {
      int s = si + sI * 2;
      float acc = 0.f;
      #pragma unroll
      for (int k = 0; k < 128; k += 4) {
        float4 wv = *reinterpret_cast<const float4*>(&Wl[h][k]);
        acc += vin[s][half * 128 + k] * wv.x + vin[s][half * 128 + k + 1] * wv.y +
               vin[s][half * 128 + k + 2] * wv.z + vin[s][half * 128 + k + 3] * wv.w;
      }
      if (half == 0) res[sI] = acc;
      else out[(size_t)(b0 + s) * H + h] = res[sI] + acc + b3[h];
    }
  }
}

// ----------------------------------------------------------------
extern "C" void kernel_launch(void* const* d_in, const int* in_sizes, int n_in,
                              void* d_out, int out_size, void* d_ws, size_t ws_size,
                              hipStream_t stream) {
  const float* x     = (const float*)d_in[0];
  const int*   batch = (const int*)d_in[1];
  const float* W1    = (const float*)d_in[2];
  const float* b1    = (const float*)d_in[3];
  const float* W2    = (const float*)d_in[4];
  const float* b2    = (const float*)d_in[5];
  const float* Wq    = (const float*)d_in[6];
  const float* bq    = (const float*)d_in[7];
  const float* W3    = (const float*)d_in[8];
  const float* b3    = (const float*)d_in[9];
  float* out = (float*)d_out;

  char* ws = (char*)d_ws;
  int*            last_idx = (int*)ws;                                    // 16 KB
  float*          A_pre    = (float*)(ws + 16384);                        // 2 MB
  float*          s_g      = (float*)(ws + 16384 + 2097152);              // 2 MB
  unsigned short* W2b      = (unsigned short*)(ws + 16384 + 2 * 2097152); // 32 KB

  k_prep<<<N_NODES / 256, 256, 0, stream>>>(batch, last_idx, W2, W2b, s_g);
  k_apre<<<B_SESS / 8, 256, 0, stream>>>(x, last_idx, W1, b1, b2, A_pre);
  k_main<<<N_NODES / (TILE * TPB), 256, 0, stream>>>(x, batch, W2b, Wq, bq, A_pre, s_g);
  k_final<<<B_SESS / 8, 256, 0, stream>>>(x, last_idx, s_g, W3, b3, out);
}